// Round 2
// baseline (483.704 us; speedup 1.0000x reference)
//
#include <hip/hip_runtime.h>

#define N_NODES 50000
#define N_EDGES 800000
#define DIN 256
#define DHID 128
#define DOUT 64

// ---------------- CSR build ----------------

__global__ void count_kernel(const int* __restrict__ ei, int* __restrict__ cnt) {
    int stride = gridDim.x * blockDim.x;
    for (int e = blockIdx.x * blockDim.x + threadIdx.x; e < N_EDGES; e += stride) {
        atomicAdd(&cnt[ei[N_EDGES + e]], 1);   // dst row of edge_index
    }
}

__global__ __launch_bounds__(1024) void scan_kernel(const int* __restrict__ cnt,
        int* __restrict__ rowptr, int* __restrict__ cursor, float* __restrict__ dis) {
    __shared__ int wsum[16];
    __shared__ int chunk_total;
    int carry = 0;
    const int tid = threadIdx.x;
    const int lane = tid & 63, wid = tid >> 6;
    for (int base = 0; base < N_NODES; base += 1024) {
        int i = base + tid;
        int v = (i < N_NODES) ? cnt[i] : 0;
        int x = v;
        #pragma unroll
        for (int off = 1; off < 64; off <<= 1) {
            int y = __shfl_up(x, off);
            if (lane >= off) x += y;
        }
        if (lane == 63) wsum[wid] = x;
        __syncthreads();
        if (tid == 0) {
            int s = 0;
            #pragma unroll
            for (int w = 0; w < 16; ++w) { int t = wsum[w]; wsum[w] = s; s += t; }
            chunk_total = s;
        }
        __syncthreads();
        int excl = carry + wsum[wid] + (x - v);
        if (i < N_NODES) {
            rowptr[i] = excl;
            cursor[i] = excl;
            dis[i] = rsqrtf((float)(v + 1));   // deg includes self-loop
        }
        carry += chunk_total;
        __syncthreads();
    }
    if (tid == 0) rowptr[N_NODES] = carry;
}

__global__ void fill_kernel(const int* __restrict__ ei, int* __restrict__ cursor,
                            int* __restrict__ col) {
    int stride = gridDim.x * blockDim.x;
    for (int e = blockIdx.x * blockDim.x + threadIdx.x; e < N_EDGES; e += stride) {
        int s = ei[e];
        int d = ei[N_EDGES + e];
        int pos = atomicAdd(&cursor[d], 1);
        col[pos] = s;
    }
}

// ---------------- weight pre-transpose ----------------
// Wt1[k][j] = W1[j][k]  (256x128);  Wct[k][o] = o<64 ? Wmu[o][k] : Wlv[o-64][k] (128x128)

__global__ void wprep_kernel(const float* __restrict__ W1, const float* __restrict__ Wmu,
                             const float* __restrict__ Wlv, float* __restrict__ Wt1,
                             float* __restrict__ Wct) {
    int tid = blockIdx.x * blockDim.x + threadIdx.x;
    if (tid < DIN * DHID) {
        int k = tid >> 7, j = tid & 127;
        Wt1[k * DHID + j] = W1[j * DIN + k];
    } else if (tid < DIN * DHID + DHID * 128) {
        int t = tid - DIN * DHID;
        int k = t >> 7, o = t & 127;
        Wct[t] = (o < 64) ? Wmu[o * DHID + k] : Wlv[(o - 64) * DHID + k];
    }
}

// ---------------- GEMM1: u1[n] = dis[n] * (x[n] @ W1^T) ----------------

__global__ __launch_bounds__(256) void gemm1_kernel(const float* __restrict__ x,
        const float* __restrict__ Wt1, const float* __restrict__ dis,
        float* __restrict__ u1) {
    __shared__ float xs[16][64];
    __shared__ float wt[64][132];
    const int tid = threadIdx.x;
    const int jg = tid & 31, npair = tid >> 5;
    const int nb = blockIdx.x * 16;
    float4 acc0 = {0.f, 0.f, 0.f, 0.f};
    float4 acc1 = {0.f, 0.f, 0.f, 0.f};
    for (int k0 = 0; k0 < DIN; k0 += 64) {
        {
            int n = tid >> 4, f4 = tid & 15;
            *(float4*)&xs[n][f4 * 4] =
                *(const float4*)(x + (size_t)(nb + n) * DIN + k0 + f4 * 4);
        }
        #pragma unroll
        for (int r = 0; r < 8; ++r) {
            int lin = tid + r * 256;
            int kk = lin >> 5, f4 = lin & 31;
            *(float4*)&wt[kk][f4 * 4] =
                *(const float4*)(Wt1 + (size_t)(k0 + kk) * DHID + f4 * 4);
        }
        __syncthreads();
        const int n0 = npair * 2, n1 = n0 + 1;
        #pragma unroll 8
        for (int k = 0; k < 64; ++k) {
            float4 w = *(const float4*)&wt[k][jg * 4];
            float x0 = xs[n0][k], x1 = xs[n1][k];
            acc0.x += x0 * w.x; acc0.y += x0 * w.y; acc0.z += x0 * w.z; acc0.w += x0 * w.w;
            acc1.x += x1 * w.x; acc1.y += x1 * w.y; acc1.z += x1 * w.z; acc1.w += x1 * w.w;
        }
        __syncthreads();
    }
    int n0g = nb + npair * 2, n1g = n0g + 1;
    float d0 = dis[n0g], d1 = dis[n1g];
    float4 o0 = {acc0.x * d0, acc0.y * d0, acc0.z * d0, acc0.w * d0};
    float4 o1 = {acc1.x * d1, acc1.y * d1, acc1.z * d1, acc1.w * d1};
    *(float4*)(u1 + (size_t)n0g * DHID + jg * 4) = o0;
    *(float4*)(u1 + (size_t)n1g * DHID + jg * 4) = o1;
}

// ---------------- pull aggregation (one wave per node) ----------------
// LAYER1: uout = dis * relu(dis*(sum + u[i]) + b1)     (produces u2)
// else  : uout = dis * (sum + u[i])                    (produces a2)

template <bool LAYER1>
__global__ __launch_bounds__(256) void pull_kernel(const int* __restrict__ rowptr,
        const int* __restrict__ col, const float* __restrict__ uin,
        const float* __restrict__ dis, const float* __restrict__ b1,
        float* __restrict__ uout) {
    const int wid = threadIdx.x >> 6, lane = threadIdx.x & 63;
    const int i = blockIdx.x * 4 + wid;
    if (i >= N_NODES) return;
    const int beg = rowptr[i], end = rowptr[i + 1];
    const int j2 = lane * 2;
    float ax = 0.f, ay = 0.f;
    for (int p = beg; p < end; ++p) {
        int c = col[p];
        const float* rp = uin + (size_t)c * DHID + j2;
        float2 v = *(const float2*)rp;
        ax += v.x; ay += v.y;
    }
    float di = dis[i];
    float2 sv = *(const float2*)(uin + (size_t)i * DHID + j2);
    float tx = di * (ax + sv.x);
    float ty = di * (ay + sv.y);
    if (LAYER1) {
        float2 b = *(const float2*)(b1 + j2);
        tx = fmaxf(tx + b.x, 0.f) * di;
        ty = fmaxf(ty + b.y, 0.f) * di;
    }
    float2 o = {tx, ty};
    *(float2*)(uout + (size_t)i * DHID + j2) = o;
}

// ---------------- GEMM2: [mu|lv] = a2 @ [Wmu|Wlv]^T + [bmu|blv] ----------------

__global__ __launch_bounds__(256) void gemm2_kernel(const float* __restrict__ A,
        const float* __restrict__ Wct, const float* __restrict__ bmu,
        const float* __restrict__ blv, float* __restrict__ out) {
    __shared__ float as_[16][64];
    __shared__ float wt[64][132];
    const int tid = threadIdx.x;
    const int jg = tid & 31, npair = tid >> 5;
    const int nb = blockIdx.x * 16;
    float4 acc0 = {0.f, 0.f, 0.f, 0.f};
    float4 acc1 = {0.f, 0.f, 0.f, 0.f};
    for (int k0 = 0; k0 < DHID; k0 += 64) {
        {
            int n = tid >> 4, f4 = tid & 15;
            *(float4*)&as_[n][f4 * 4] =
                *(const float4*)(A + (size_t)(nb + n) * DHID + k0 + f4 * 4);
        }
        #pragma unroll
        for (int r = 0; r < 8; ++r) {
            int lin = tid + r * 256;
            int kk = lin >> 5, f4 = lin & 31;
            *(float4*)&wt[kk][f4 * 4] =
                *(const float4*)(Wct + (size_t)(k0 + kk) * 128 + f4 * 4);
        }
        __syncthreads();
        const int n0 = npair * 2, n1 = n0 + 1;
        #pragma unroll 8
        for (int k = 0; k < 64; ++k) {
            float4 w = *(const float4*)&wt[k][jg * 4];
            float a0 = as_[n0][k], a1 = as_[n1][k];
            acc0.x += a0 * w.x; acc0.y += a0 * w.y; acc0.z += a0 * w.z; acc0.w += a0 * w.w;
            acc1.x += a1 * w.x; acc1.y += a1 * w.y; acc1.z += a1 * w.z; acc1.w += a1 * w.w;
        }
        __syncthreads();
    }
    const int n0g = nb + npair * 2, n1g = n0g + 1;
    const int j0 = jg * 4;
    if (jg < 16) {
        float4 b = *(const float4*)(bmu + j0);
        float4 o0 = {acc0.x + b.x, acc0.y + b.y, acc0.z + b.z, acc0.w + b.w};
        float4 o1 = {acc1.x + b.x, acc1.y + b.y, acc1.z + b.z, acc1.w + b.w};
        *(float4*)(out + (size_t)n0g * DOUT + j0) = o0;
        *(float4*)(out + (size_t)n1g * DOUT + j0) = o1;
    } else {
        const int jl = j0 - 64;
        float4 b = *(const float4*)(blv + jl);
        float4 o0 = {acc0.x + b.x, acc0.y + b.y, acc0.z + b.z, acc0.w + b.w};
        float4 o1 = {acc1.x + b.x, acc1.y + b.y, acc1.z + b.z, acc1.w + b.w};
        *(float4*)(out + (size_t)N_NODES * DOUT + (size_t)n0g * DOUT + jl) = o0;
        *(float4*)(out + (size_t)N_NODES * DOUT + (size_t)n1g * DOUT + jl) = o1;
    }
}

// ---------------- launcher ----------------

extern "C" void kernel_launch(void* const* d_in, const int* in_sizes, int n_in,
                              void* d_out, int out_size, void* d_ws, size_t ws_size,
                              hipStream_t stream) {
    const float* x   = (const float*)d_in[0];
    const int*   ei  = (const int*)d_in[1];     // [2, E] row-major: src then dst
    const float* W1  = (const float*)d_in[2];
    const float* b1  = (const float*)d_in[3];
    const float* Wmu = (const float*)d_in[4];
    const float* bmu = (const float*)d_in[5];
    const float* Wlv = (const float*)d_in[6];
    const float* blv = (const float*)d_in[7];
    float* out = (float*)d_out;

    char* ws = (char*)d_ws;
    size_t off = 0;
    auto alloc = [&](size_t bytes) -> char* {
        char* p = ws + off;
        off += (bytes + 255) & ~(size_t)255;
        return p;
    };
    int*   cnt    = (int*)  alloc((size_t)N_NODES * 4);
    int*   rowptr = (int*)  alloc((size_t)(N_NODES + 1) * 4);
    int*   cursor = (int*)  alloc((size_t)N_NODES * 4);
    float* dis    = (float*)alloc((size_t)N_NODES * 4);
    int*   col    = (int*)  alloc((size_t)N_EDGES * 4);
    float* Wt1    = (float*)alloc((size_t)DIN * DHID * 4);
    float* Wct    = (float*)alloc((size_t)DHID * 128 * 4);
    float* u1     = (float*)alloc((size_t)N_NODES * DHID * 4);   // reused as a2
    float* u2     = (float*)alloc((size_t)N_NODES * DHID * 4);
    float* a2 = u1;   // u1 is dead after pull1; alias to save workspace

    hipMemsetAsync(cnt, 0, (size_t)N_NODES * 4, stream);
    count_kernel<<<1024, 256, 0, stream>>>(ei, cnt);
    scan_kernel<<<1, 1024, 0, stream>>>(cnt, rowptr, cursor, dis);
    wprep_kernel<<<192, 256, 0, stream>>>(W1, Wmu, Wlv, Wt1, Wct);
    fill_kernel<<<1024, 256, 0, stream>>>(ei, cursor, col);
    gemm1_kernel<<<N_NODES / 16, 256, 0, stream>>>(x, Wt1, dis, u1);
    pull_kernel<true><<<N_NODES / 4, 256, 0, stream>>>(rowptr, col, u1, dis, b1, u2);
    pull_kernel<false><<<N_NODES / 4, 256, 0, stream>>>(rowptr, col, u2, dis, nullptr, a2);
    gemm2_kernel<<<N_NODES / 16, 256, 0, stream>>>(a2, Wct, bmu, blv, out);
}

// Round 3
// 412.286 us; speedup vs baseline: 1.1732x; 1.1732x over previous
//
#include <hip/hip_runtime.h>

#define N_NODES 50000
#define N_EDGES 800000
#define DIN 256
#define DHID 128
#define DOUT 64
#define NB_SCAN 49   // ceil(50000/1024)

typedef __attribute__((ext_vector_type(8))) short short8;
typedef __attribute__((ext_vector_type(4))) float f32x4;

static __device__ __forceinline__ short f2bf(float f) {
    union { float f; unsigned u; } v; v.f = f;
    unsigned r = v.u + 0x7FFFu + ((v.u >> 16) & 1u);   // RNE
    return (short)(r >> 16);
}
static __device__ __forceinline__ float bflo(unsigned p) {
    union { unsigned u; float f; } v; v.u = p << 16; return v.f;
}
static __device__ __forceinline__ float bfhi(unsigned p) {
    union { unsigned u; float f; } v; v.u = p & 0xFFFF0000u; return v.f;
}

// ---------------- CSR build ----------------

__global__ void count_kernel(const int* __restrict__ ei, int* __restrict__ cnt) {
    int stride = gridDim.x * blockDim.x;
    for (int e = blockIdx.x * blockDim.x + threadIdx.x; e < N_EDGES; e += stride) {
        atomicAdd(&cnt[ei[N_EDGES + e]], 1);   // dst row
    }
}

__global__ __launch_bounds__(1024) void bsum_kernel(const int* __restrict__ cnt,
                                                    int* __restrict__ bsum) {
    __shared__ int ws[16];
    int tid = threadIdx.x, i = blockIdx.x * 1024 + tid;
    int v = (i < N_NODES) ? cnt[i] : 0;
    #pragma unroll
    for (int off = 32; off >= 1; off >>= 1) v += __shfl_xor(v, off);
    if ((tid & 63) == 0) ws[tid >> 6] = v;
    __syncthreads();
    if (tid == 0) {
        int s = 0;
        #pragma unroll
        for (int w = 0; w < 16; ++w) s += ws[w];
        bsum[blockIdx.x] = s;
    }
}

__global__ void bscan_kernel(const int* __restrict__ bsum, int* __restrict__ bo,
                             int* __restrict__ rowptr) {
    int l = threadIdx.x;   // 64 threads
    int v = (l < NB_SCAN) ? bsum[l] : 0;
    int x = v;
    #pragma unroll
    for (int off = 1; off < 64; off <<= 1) {
        int y = __shfl_up(x, off);
        if (l >= off) x += y;
    }
    if (l < NB_SCAN) bo[l] = x - v;
    if (l == 63) rowptr[N_NODES] = x;
}

__global__ __launch_bounds__(1024) void scan_apply_kernel(const int* __restrict__ cnt,
        const int* __restrict__ bo, int* __restrict__ rowptr,
        int* __restrict__ cursor, float* __restrict__ dis) {
    __shared__ int wsum[16];
    int tid = threadIdx.x, i = blockIdx.x * 1024 + tid;
    int lane = tid & 63, wid = tid >> 6;
    int v = (i < N_NODES) ? cnt[i] : 0;
    int x = v;
    #pragma unroll
    for (int off = 1; off < 64; off <<= 1) {
        int y = __shfl_up(x, off);
        if (lane >= off) x += y;
    }
    if (lane == 63) wsum[wid] = x;
    __syncthreads();
    if (tid == 0) {
        int s = 0;
        #pragma unroll
        for (int w = 0; w < 16; ++w) { int t = wsum[w]; wsum[w] = s; s += t; }
    }
    __syncthreads();
    int excl = bo[blockIdx.x] + wsum[wid] + (x - v);
    if (i < N_NODES) {
        rowptr[i] = excl;
        cursor[i] = excl;
        dis[i] = rsqrtf((float)(v + 1));
    }
}

__global__ void fill_kernel(const int* __restrict__ ei, int* __restrict__ cursor,
                            int* __restrict__ col) {
    int stride = gridDim.x * blockDim.x;
    for (int e = blockIdx.x * blockDim.x + threadIdx.x; e < N_EDGES; e += stride) {
        int s = ei[e];
        int d = ei[N_EDGES + e];
        int pos = atomicAdd(&cursor[d], 1);
        col[pos] = s;
    }
}

// ---------------- weight prep ----------------
// W1b = bf16(W1) row-major [128][256] (== B-operand layout: B[k][col]=W1[col][k])
// Wct[k][o] f32: o<64 ? Wmu[o][k] : Wlv[o-64][k]   (128x128)

__global__ void wprep_kernel(const float* __restrict__ W1, const float* __restrict__ Wmu,
                             const float* __restrict__ Wlv, short* __restrict__ W1b,
                             float* __restrict__ Wct) {
    int tid = blockIdx.x * blockDim.x + threadIdx.x;
    if (tid < DHID * DIN) {
        W1b[tid] = f2bf(W1[tid]);
    } else if (tid < DHID * DIN + DHID * 128) {
        int t = tid - DHID * DIN;
        int k = t >> 7, o = t & 127;
        Wct[t] = (o < 64) ? Wmu[o * DHID + k] : Wlv[(o - 64) * DHID + k];
    }
}

// ---------------- GEMM1 (MFMA bf16): u1b[n] = bf16(dis[n] * (x[n] @ W1^T)) ----------------
// block = 4 waves, BM = 64 rows (16/wave), BN = 128 (full), K = 256.
// A-frag: lane holds x[r0][k0..k0+7], r0 = nb+16w+(lane&15), k0 = ks*32+(lane>>4)*8
// B-frag: lane holds W1^T[k][col] = W1b[16c+(lane&15)][k0..k0+7]
// C/D: row = (lane>>4)*4+e, col = lane&15  (m89-verified)

__global__ __launch_bounds__(256) void gemm1_mfma_kernel(const float* __restrict__ x,
        const short* __restrict__ W1b, const float* __restrict__ dis,
        short* __restrict__ u1b) {
    const int lane = threadIdx.x & 63, w = threadIdx.x >> 6;
    const int l15 = lane & 15, kg = lane >> 4;
    const int nb = blockIdx.x * 64;
    const int r0 = nb + w * 16 + l15;
    const bool valid = r0 < N_NODES;
    const float* xrow = x + (size_t)r0 * DIN;

    f32x4 acc[8] = {};
    #pragma unroll
    for (int ks = 0; ks < 8; ++ks) {
        const int k0 = ks * 32 + kg * 8;
        short8 a;
        if (valid) {
            float4 f0 = *(const float4*)(xrow + k0);
            float4 f1 = *(const float4*)(xrow + k0 + 4);
            a[0] = f2bf(f0.x); a[1] = f2bf(f0.y); a[2] = f2bf(f0.z); a[3] = f2bf(f0.w);
            a[4] = f2bf(f1.x); a[5] = f2bf(f1.y); a[6] = f2bf(f1.z); a[7] = f2bf(f1.w);
        } else {
            a = short8{0, 0, 0, 0, 0, 0, 0, 0};
        }
        #pragma unroll
        for (int c = 0; c < 8; ++c) {
            short8 b = *(const short8*)(W1b + (size_t)(c * 16 + l15) * DIN + k0);
            acc[c] = __builtin_amdgcn_mfma_f32_16x16x32_bf16(a, b, acc[c], 0, 0, 0);
        }
    }

    const int rb = nb + w * 16 + kg * 4;
    float dv[4];
    #pragma unroll
    for (int e = 0; e < 4; ++e) dv[e] = (rb + e < N_NODES) ? dis[rb + e] : 0.f;
    #pragma unroll
    for (int c = 0; c < 8; ++c) {
        #pragma unroll
        for (int e = 0; e < 4; ++e) {
            int r = rb + e;
            if (r < N_NODES)
                u1b[(size_t)r * DHID + c * 16 + l15] = f2bf(acc[c][e] * dv[e]);
        }
    }
}

// ---------------- pull aggregation (one wave per node, bf16 in) ----------------
// LAYER1: u2b = bf16(dis * relu(dis*(sum + self) + b1))
// else  : a2  = dis * (sum + self)   (f32 out)

template <bool LAYER1>
__global__ __launch_bounds__(256) void pull_kernel(const int* __restrict__ rowptr,
        const int* __restrict__ col, const short* __restrict__ uin,
        const float* __restrict__ dis, const float* __restrict__ b1,
        void* __restrict__ uout) {
    const int wid = threadIdx.x >> 6, lane = threadIdx.x & 63;
    const int i = blockIdx.x * 4 + wid;
    if (i >= N_NODES) return;
    const int beg = rowptr[i], end = rowptr[i + 1];
    const int j2 = lane * 2;
    float ax = 0.f, ay = 0.f;
    for (int p = beg; p < end; ++p) {
        int c = col[p];
        unsigned v = *(const unsigned*)(uin + (size_t)c * DHID + j2);
        ax += bflo(v);
        ay += bfhi(v);
    }
    float di = dis[i];
    unsigned sv = *(const unsigned*)(uin + (size_t)i * DHID + j2);
    float tx = di * (ax + bflo(sv));
    float ty = di * (ay + bfhi(sv));
    if (LAYER1) {
        float2 b = *(const float2*)(b1 + j2);
        tx = fmaxf(tx + b.x, 0.f) * di;
        ty = fmaxf(ty + b.y, 0.f) * di;
        unsigned o = ((unsigned)(unsigned short)f2bf(tx)) |
                     (((unsigned)(unsigned short)f2bf(ty)) << 16);
        *((unsigned*)uout + (size_t)i * (DHID / 2) + lane) = o;
    } else {
        float2 o = {tx, ty};
        *(float2*)((float*)uout + (size_t)i * DHID + j2) = o;
    }
}

// ---------------- GEMM2 (f32): [mu|lv] = a2 @ [Wmu|Wlv]^T + [bmu|blv] ----------------

__global__ __launch_bounds__(256) void gemm2_kernel(const float* __restrict__ A,
        const float* __restrict__ Wct, const float* __restrict__ bmu,
        const float* __restrict__ blv, float* __restrict__ out) {
    __shared__ float as_[16][64];
    __shared__ float wt[64][132];
    const int tid = threadIdx.x;
    const int jg = tid & 31, npair = tid >> 5;
    const int nb = blockIdx.x * 16;
    float4 acc0 = {0.f, 0.f, 0.f, 0.f};
    float4 acc1 = {0.f, 0.f, 0.f, 0.f};
    for (int k0 = 0; k0 < DHID; k0 += 64) {
        {
            int n = tid >> 4, f4 = tid & 15;
            *(float4*)&as_[n][f4 * 4] =
                *(const float4*)(A + (size_t)(nb + n) * DHID + k0 + f4 * 4);
        }
        #pragma unroll
        for (int r = 0; r < 8; ++r) {
            int lin = tid + r * 256;
            int kk = lin >> 5, f4 = lin & 31;
            *(float4*)&wt[kk][f4 * 4] =
                *(const float4*)(Wct + (size_t)(k0 + kk) * 128 + f4 * 4);
        }
        __syncthreads();
        const int n0 = npair * 2, n1 = n0 + 1;
        #pragma unroll 8
        for (int k = 0; k < 64; ++k) {
            float4 w = *(const float4*)&wt[k][jg * 4];
            float a0 = as_[n0][k], a1 = as_[n1][k];
            acc0.x += a0 * w.x; acc0.y += a0 * w.y; acc0.z += a0 * w.z; acc0.w += a0 * w.w;
            acc1.x += a1 * w.x; acc1.y += a1 * w.y; acc1.z += a1 * w.z; acc1.w += a1 * w.w;
        }
        __syncthreads();
    }
    const int n0g = nb + npair * 2, n1g = n0g + 1;
    const int j0 = jg * 4;
    if (jg < 16) {
        float4 b = *(const float4*)(bmu + j0);
        float4 o0 = {acc0.x + b.x, acc0.y + b.y, acc0.z + b.z, acc0.w + b.w};
        float4 o1 = {acc1.x + b.x, acc1.y + b.y, acc1.z + b.z, acc1.w + b.w};
        *(float4*)(out + (size_t)n0g * DOUT + j0) = o0;
        *(float4*)(out + (size_t)n1g * DOUT + j0) = o1;
    } else {
        const int jl = j0 - 64;
        float4 b = *(const float4*)(blv + jl);
        float4 o0 = {acc0.x + b.x, acc0.y + b.y, acc0.z + b.z, acc0.w + b.w};
        float4 o1 = {acc1.x + b.x, acc1.y + b.y, acc1.z + b.z, acc1.w + b.w};
        *(float4*)(out + (size_t)N_NODES * DOUT + (size_t)n0g * DOUT + jl) = o0;
        *(float4*)(out + (size_t)N_NODES * DOUT + (size_t)n1g * DOUT + jl) = o1;
    }
}

// ---------------- launcher ----------------

extern "C" void kernel_launch(void* const* d_in, const int* in_sizes, int n_in,
                              void* d_out, int out_size, void* d_ws, size_t ws_size,
                              hipStream_t stream) {
    const float* x   = (const float*)d_in[0];
    const int*   ei  = (const int*)d_in[1];
    const float* W1  = (const float*)d_in[2];
    const float* b1  = (const float*)d_in[3];
    const float* Wmu = (const float*)d_in[4];
    const float* bmu = (const float*)d_in[5];
    const float* Wlv = (const float*)d_in[6];
    const float* blv = (const float*)d_in[7];
    float* out = (float*)d_out;

    char* ws = (char*)d_ws;
    size_t off = 0;
    auto alloc = [&](size_t bytes) -> char* {
        char* p = ws + off;
        off += (bytes + 255) & ~(size_t)255;
        return p;
    };
    int*   cnt    = (int*)  alloc((size_t)N_NODES * 4);
    int*   rowptr = (int*)  alloc((size_t)(N_NODES + 1) * 4);
    int*   cursor = (int*)  alloc((size_t)N_NODES * 4);
    float* dis    = (float*)alloc((size_t)N_NODES * 4);
    int*   col    = (int*)  alloc((size_t)N_EDGES * 4);
    int*   bsum   = (int*)  alloc((size_t)NB_SCAN * 4);
    int*   bo     = (int*)  alloc((size_t)NB_SCAN * 4);
    short* W1b    = (short*)alloc((size_t)DHID * DIN * 2);
    float* Wct    = (float*)alloc((size_t)DHID * 128 * 4);
    short* u1b    = (short*)alloc((size_t)N_NODES * DHID * 2);
    short* u2b    = (short*)alloc((size_t)N_NODES * DHID * 2);
    float* a2     = (float*)alloc((size_t)N_NODES * DHID * 4);

    hipMemsetAsync(cnt, 0, (size_t)N_NODES * 4, stream);
    wprep_kernel<<<192, 256, 0, stream>>>(W1, Wmu, Wlv, W1b, Wct);
    count_kernel<<<1024, 256, 0, stream>>>(ei, cnt);
    bsum_kernel<<<NB_SCAN, 1024, 0, stream>>>(cnt, bsum);
    bscan_kernel<<<1, 64, 0, stream>>>(bsum, bo, rowptr);
    scan_apply_kernel<<<NB_SCAN, 1024, 0, stream>>>(cnt, bo, rowptr, cursor, dis);
    fill_kernel<<<1024, 256, 0, stream>>>(ei, cursor, col);
    gemm1_mfma_kernel<<<(N_NODES + 63) / 64, 256, 0, stream>>>(x, W1b, dis, u1b);
    pull_kernel<true><<<N_NODES / 4, 256, 0, stream>>>(rowptr, col, u1b, dis, b1, u2b);
    pull_kernel<false><<<N_NODES / 4, 256, 0, stream>>>(rowptr, col, u2b, dis, nullptr, a2);
    gemm2_kernel<<<N_NODES / 16, 256, 0, stream>>>(a2, Wct, bmu, blv, out);
}

// Round 4
// 325.047 us; speedup vs baseline: 1.4881x; 1.2684x over previous
//
#include <hip/hip_runtime.h>

#define N_NODES 50000
#define N_EDGES 800000
#define DIN 256
#define DHID 128
#define DOUT 64
#define NB_SCAN 49   // ceil(50000/1024)

typedef __attribute__((ext_vector_type(8))) short short8;
typedef __attribute__((ext_vector_type(4))) float f32x4;

static __device__ __forceinline__ short f2bf(float f) {
    union { float f; unsigned u; } v; v.f = f;
    unsigned r = v.u + 0x7FFFu + ((v.u >> 16) & 1u);   // RNE
    return (short)(r >> 16);
}
static __device__ __forceinline__ float bflo(unsigned p) {
    union { unsigned u; float f; } v; v.u = p << 16; return v.f;
}
static __device__ __forceinline__ float bfhi(unsigned p) {
    union { unsigned u; float f; } v; v.u = p & 0xFFFF0000u; return v.f;
}

// ---------------- CSR build ----------------

__global__ void count_kernel(const int* __restrict__ ei, int* __restrict__ cnt) {
    int stride = gridDim.x * blockDim.x;
    for (int e = blockIdx.x * blockDim.x + threadIdx.x; e < N_EDGES; e += stride) {
        atomicAdd(&cnt[ei[N_EDGES + e]], 1);   // dst row
    }
}

__global__ __launch_bounds__(1024) void bsum_kernel(const int* __restrict__ cnt,
                                                    int* __restrict__ bsum) {
    __shared__ int ws[16];
    int tid = threadIdx.x, i = blockIdx.x * 1024 + tid;
    int v = (i < N_NODES) ? cnt[i] : 0;
    #pragma unroll
    for (int off = 32; off >= 1; off >>= 1) v += __shfl_xor(v, off);
    if ((tid & 63) == 0) ws[tid >> 6] = v;
    __syncthreads();
    if (tid == 0) {
        int s = 0;
        #pragma unroll
        for (int w = 0; w < 16; ++w) s += ws[w];
        bsum[blockIdx.x] = s;
    }
}

__global__ void bscan_kernel(const int* __restrict__ bsum, int* __restrict__ bo,
                             int* __restrict__ rowptr) {
    int l = threadIdx.x;   // 64 threads
    int v = (l < NB_SCAN) ? bsum[l] : 0;
    int x = v;
    #pragma unroll
    for (int off = 1; off < 64; off <<= 1) {
        int y = __shfl_up(x, off);
        if (l >= off) x += y;
    }
    if (l < NB_SCAN) bo[l] = x - v;
    if (l == 63) rowptr[N_NODES] = x;
}

__global__ __launch_bounds__(1024) void scan_apply_kernel(const int* __restrict__ cnt,
        const int* __restrict__ bo, int* __restrict__ rowptr,
        int* __restrict__ cursor, float* __restrict__ dis) {
    __shared__ int wsum[16];
    int tid = threadIdx.x, i = blockIdx.x * 1024 + tid;
    int lane = tid & 63, wid = tid >> 6;
    int v = (i < N_NODES) ? cnt[i] : 0;
    int x = v;
    #pragma unroll
    for (int off = 1; off < 64; off <<= 1) {
        int y = __shfl_up(x, off);
        if (lane >= off) x += y;
    }
    if (lane == 63) wsum[wid] = x;
    __syncthreads();
    if (tid == 0) {
        int s = 0;
        #pragma unroll
        for (int w = 0; w < 16; ++w) { int t = wsum[w]; wsum[w] = s; s += t; }
    }
    __syncthreads();
    int excl = bo[blockIdx.x] + wsum[wid] + (x - v);
    if (i < N_NODES) {
        rowptr[i] = excl;
        cursor[i] = excl;
        dis[i] = rsqrtf((float)(v + 1));
    }
}

__global__ void fill_kernel(const int* __restrict__ ei, int* __restrict__ cursor,
                            int* __restrict__ col) {
    int stride = gridDim.x * blockDim.x;
    for (int e = blockIdx.x * blockDim.x + threadIdx.x; e < N_EDGES; e += stride) {
        int s = ei[e];
        int d = ei[N_EDGES + e];
        int pos = atomicAdd(&cursor[d], 1);
        col[pos] = s;
    }
}

// ---------------- weight prep ----------------
// W1b  = bf16(W1)  row-major [128][256]  (B-operand layout for gemm1)
// Wctb = bf16 concat rows: [0..63]=Wmu[64][128], [64..127]=Wlv  (B-operand for gemm2)

__global__ void wprep_kernel(const float* __restrict__ W1, const float* __restrict__ Wmu,
                             const float* __restrict__ Wlv, short* __restrict__ W1b,
                             short* __restrict__ Wctb) {
    int tid = blockIdx.x * blockDim.x + threadIdx.x;
    if (tid < DHID * DIN) {
        W1b[tid] = f2bf(W1[tid]);
    } else if (tid < DHID * DIN + 2 * DOUT * DHID) {
        int t = tid - DHID * DIN;
        Wctb[t] = f2bf((t < DOUT * DHID) ? Wmu[t] : Wlv[t - DOUT * DHID]);
    }
}

// ---------------- GEMM1 (MFMA bf16): u1b[n] = bf16(dis[n] * (x[n] @ W1^T)) ----------------
// 4 waves, BM=64 rows (16/wave), BN=128, K=256. Layout m89-verified (R3 passed).

__global__ __launch_bounds__(256) void gemm1_mfma_kernel(const float* __restrict__ x,
        const short* __restrict__ W1b, const float* __restrict__ dis,
        short* __restrict__ u1b) {
    const int lane = threadIdx.x & 63, w = threadIdx.x >> 6;
    const int l15 = lane & 15, kg = lane >> 4;
    const int nb = blockIdx.x * 64;
    const int r0 = nb + w * 16 + l15;
    const bool valid = r0 < N_NODES;
    const float* xrow = x + (size_t)r0 * DIN;

    f32x4 acc[8] = {};
    #pragma unroll
    for (int ks = 0; ks < 8; ++ks) {
        const int k0 = ks * 32 + kg * 8;
        short8 a;
        if (valid) {
            float4 f0 = *(const float4*)(xrow + k0);
            float4 f1 = *(const float4*)(xrow + k0 + 4);
            a[0] = f2bf(f0.x); a[1] = f2bf(f0.y); a[2] = f2bf(f0.z); a[3] = f2bf(f0.w);
            a[4] = f2bf(f1.x); a[5] = f2bf(f1.y); a[6] = f2bf(f1.z); a[7] = f2bf(f1.w);
        } else {
            a = short8{0, 0, 0, 0, 0, 0, 0, 0};
        }
        #pragma unroll
        for (int c = 0; c < 8; ++c) {
            short8 b = *(const short8*)(W1b + (size_t)(c * 16 + l15) * DIN + k0);
            acc[c] = __builtin_amdgcn_mfma_f32_16x16x32_bf16(a, b, acc[c], 0, 0, 0);
        }
    }

    const int rb = nb + w * 16 + kg * 4;
    float dv[4];
    #pragma unroll
    for (int e = 0; e < 4; ++e) dv[e] = (rb + e < N_NODES) ? dis[rb + e] : 0.f;
    #pragma unroll
    for (int c = 0; c < 8; ++c) {
        #pragma unroll
        for (int e = 0; e < 4; ++e) {
            int r = rb + e;
            if (r < N_NODES)
                u1b[(size_t)r * DHID + c * 16 + l15] = f2bf(acc[c][e] * dv[e]);
        }
    }
}

// ---------------- pull aggregation (one wave per node, bf16 in, bf16 out) ----------------
// col indices hoisted to registers (1 vector load / 64 edges, shfl-broadcast),
// gather unrolled x4 => 4 independent 256B row-loads in flight per wave.
// LAYER1: u2b = bf16(dis * relu(dis*(sum + self) + b1))
// else  : a2b = bf16(dis * (sum + self))

template <bool LAYER1>
__global__ __launch_bounds__(256) void pull_kernel(const int* __restrict__ rowptr,
        const int* __restrict__ col, const short* __restrict__ uin,
        const float* __restrict__ dis, const float* __restrict__ b1,
        unsigned* __restrict__ uout) {
    const int wid = threadIdx.x >> 6, lane = threadIdx.x & 63;
    const int i = blockIdx.x * 4 + wid;
    if (i >= N_NODES) return;
    const int beg = rowptr[i], end = rowptr[i + 1];
    const unsigned* __restrict__ up = (const unsigned*)uin;   // row stride 64 dwords
    float ax = 0.f, ay = 0.f;
    for (int base = beg; base < end; base += 64) {
        const int rem = end - base;
        const int m = rem < 64 ? rem : 64;
        int cv = (lane < m) ? col[base + lane] : 0;
        int t = 0;
        for (; t + 4 <= m; t += 4) {
            int c0 = __shfl(cv, t);
            int c1 = __shfl(cv, t + 1);
            int c2 = __shfl(cv, t + 2);
            int c3 = __shfl(cv, t + 3);
            unsigned v0 = up[(size_t)c0 * 64 + lane];
            unsigned v1 = up[(size_t)c1 * 64 + lane];
            unsigned v2 = up[(size_t)c2 * 64 + lane];
            unsigned v3 = up[(size_t)c3 * 64 + lane];
            ax += bflo(v0); ay += bfhi(v0);
            ax += bflo(v1); ay += bfhi(v1);
            ax += bflo(v2); ay += bfhi(v2);
            ax += bflo(v3); ay += bfhi(v3);
        }
        for (; t < m; ++t) {
            int c = __shfl(cv, t);
            unsigned v = up[(size_t)c * 64 + lane];
            ax += bflo(v); ay += bfhi(v);
        }
    }
    const float di = dis[i];
    const unsigned sv = up[(size_t)i * 64 + lane];
    float tx = di * (ax + bflo(sv));
    float ty = di * (ay + bfhi(sv));
    if (LAYER1) {
        float2 b = *(const float2*)(b1 + lane * 2);
        tx = fmaxf(tx + b.x, 0.f) * di;
        ty = fmaxf(ty + b.y, 0.f) * di;
    }
    unsigned o = ((unsigned)(unsigned short)f2bf(tx)) |
                 (((unsigned)(unsigned short)f2bf(ty)) << 16);
    uout[(size_t)i * 64 + lane] = o;
}

// ---------------- GEMM2 (MFMA bf16): [mu|lv] = a2b @ Wctb^T + [bmu|blv] ----------------
// Same fragment pattern as gemm1; K=128, 128 output cols (64 mu | 64 lv).

__global__ __launch_bounds__(256) void gemm2_mfma_kernel(const short* __restrict__ a2b,
        const short* __restrict__ Wctb, const float* __restrict__ bmu,
        const float* __restrict__ blv, float* __restrict__ out) {
    const int lane = threadIdx.x & 63, w = threadIdx.x >> 6;
    const int l15 = lane & 15, kg = lane >> 4;
    const int nb = blockIdx.x * 64;
    const int r0 = nb + w * 16 + l15;
    const bool valid = r0 < N_NODES;
    const short* arow = a2b + (size_t)r0 * DHID;

    f32x4 acc[8] = {};
    #pragma unroll
    for (int ks = 0; ks < 4; ++ks) {
        const int k0 = ks * 32 + kg * 8;
        short8 a = valid ? *(const short8*)(arow + k0)
                         : short8{0, 0, 0, 0, 0, 0, 0, 0};
        #pragma unroll
        for (int c = 0; c < 8; ++c) {
            short8 b = *(const short8*)(Wctb + (size_t)(c * 16 + l15) * DHID + k0);
            acc[c] = __builtin_amdgcn_mfma_f32_16x16x32_bf16(a, b, acc[c], 0, 0, 0);
        }
    }

    float bias[8];
    #pragma unroll
    for (int c = 0; c < 8; ++c) {
        int j = c * 16 + l15;
        bias[c] = (j < DOUT) ? bmu[j] : blv[j - DOUT];
    }
    const int rb = nb + w * 16 + kg * 4;
    #pragma unroll
    for (int c = 0; c < 8; ++c) {
        const int j = c * 16 + l15;
        float* dst = (j < DOUT) ? (out + (size_t)0 * N_NODES * DOUT + j)
                                : (out + (size_t)N_NODES * DOUT + (j - DOUT));
        #pragma unroll
        for (int e = 0; e < 4; ++e) {
            int r = rb + e;
            if (r < N_NODES)
                dst[(size_t)r * DOUT] = acc[c][e] + bias[c];
        }
    }
}

// ---------------- launcher ----------------

extern "C" void kernel_launch(void* const* d_in, const int* in_sizes, int n_in,
                              void* d_out, int out_size, void* d_ws, size_t ws_size,
                              hipStream_t stream) {
    const float* x   = (const float*)d_in[0];
    const int*   ei  = (const int*)d_in[1];
    const float* W1  = (const float*)d_in[2];
    const float* b1  = (const float*)d_in[3];
    const float* Wmu = (const float*)d_in[4];
    const float* bmu = (const float*)d_in[5];
    const float* Wlv = (const float*)d_in[6];
    const float* blv = (const float*)d_in[7];
    float* out = (float*)d_out;

    char* ws = (char*)d_ws;
    size_t off = 0;
    auto alloc = [&](size_t bytes) -> char* {
        char* p = ws + off;
        off += (bytes + 255) & ~(size_t)255;
        return p;
    };
    int*   cnt    = (int*)  alloc((size_t)N_NODES * 4);
    int*   rowptr = (int*)  alloc((size_t)(N_NODES + 1) * 4);
    int*   cursor = (int*)  alloc((size_t)N_NODES * 4);
    float* dis    = (float*)alloc((size_t)N_NODES * 4);
    int*   col    = (int*)  alloc((size_t)N_EDGES * 4);
    int*   bsum   = (int*)  alloc((size_t)NB_SCAN * 4);
    int*   bo     = (int*)  alloc((size_t)NB_SCAN * 4);
    short* W1b    = (short*)alloc((size_t)DHID * DIN * 2);
    short* Wctb   = (short*)alloc((size_t)2 * DOUT * DHID * 2);
    short* u1b    = (short*)alloc((size_t)N_NODES * DHID * 2);
    short* u2b    = (short*)alloc((size_t)N_NODES * DHID * 2);
    short* a2b    = (short*)alloc((size_t)N_NODES * DHID * 2);

    hipMemsetAsync(cnt, 0, (size_t)N_NODES * 4, stream);
    wprep_kernel<<<192, 256, 0, stream>>>(W1, Wmu, Wlv, W1b, Wctb);
    count_kernel<<<1024, 256, 0, stream>>>(ei, cnt);
    bsum_kernel<<<NB_SCAN, 1024, 0, stream>>>(cnt, bsum);
    bscan_kernel<<<1, 64, 0, stream>>>(bsum, bo, rowptr);
    scan_apply_kernel<<<NB_SCAN, 1024, 0, stream>>>(cnt, bo, rowptr, cursor, dis);
    fill_kernel<<<1024, 256, 0, stream>>>(ei, cursor, col);
    gemm1_mfma_kernel<<<(N_NODES + 63) / 64, 256, 0, stream>>>(x, W1b, dis, u1b);
    pull_kernel<true><<<N_NODES / 4, 256, 0, stream>>>(rowptr, col, u1b, dis, b1,
                                                       (unsigned*)u2b);
    pull_kernel<false><<<N_NODES / 4, 256, 0, stream>>>(rowptr, col, u2b, dis, nullptr,
                                                        (unsigned*)a2b);
    gemm2_mfma_kernel<<<(N_NODES + 63) / 64, 256, 0, stream>>>(a2b, Wctb, bmu, blv, out);
}

// Round 5
// 274.427 us; speedup vs baseline: 1.7626x; 1.1845x over previous
//
#include <hip/hip_runtime.h>

#define N_NODES 50000
#define N_EDGES 800000
#define DIN 256
#define DHID 128
#define DOUT 64
#define NB_SCAN 49   // ceil(50000/1024)

typedef __attribute__((ext_vector_type(8))) short short8;
typedef __attribute__((ext_vector_type(4))) float f32x4;

static __device__ __forceinline__ short f2bf(float f) {
    union { float f; unsigned u; } v; v.f = f;
    unsigned r = v.u + 0x7FFFu + ((v.u >> 16) & 1u);   // RNE
    return (short)(r >> 16);
}
static __device__ __forceinline__ float bflo(unsigned p) {
    union { unsigned u; float f; } v; v.u = p << 16; return v.f;
}
static __device__ __forceinline__ float bfhi(unsigned p) {
    union { unsigned u; float f; } v; v.u = p & 0xFFFF0000u; return v.f;
}

// ---------------- CSR build ----------------
// Pass 1: per-dst count; also record each edge's within-row slot (atomic return).

__global__ void count_kernel(const int* __restrict__ ei, int* __restrict__ cnt,
                             int* __restrict__ loc) {
    int stride = gridDim.x * blockDim.x;
    for (int e = blockIdx.x * blockDim.x + threadIdx.x; e < N_EDGES; e += stride) {
        loc[e] = atomicAdd(&cnt[ei[N_EDGES + e]], 1);
    }
}

__global__ __launch_bounds__(1024) void bsum_kernel(const int* __restrict__ cnt,
                                                    int* __restrict__ bsum) {
    __shared__ int ws[16];
    int tid = threadIdx.x, i = blockIdx.x * 1024 + tid;
    int v = (i < N_NODES) ? cnt[i] : 0;
    #pragma unroll
    for (int off = 32; off >= 1; off >>= 1) v += __shfl_xor(v, off);
    if ((tid & 63) == 0) ws[tid >> 6] = v;
    __syncthreads();
    if (tid == 0) {
        int s = 0;
        #pragma unroll
        for (int w = 0; w < 16; ++w) s += ws[w];
        bsum[blockIdx.x] = s;
    }
}

__global__ void bscan_kernel(const int* __restrict__ bsum, int* __restrict__ bo,
                             int* __restrict__ rowptr) {
    int l = threadIdx.x;   // 64 threads
    int v = (l < NB_SCAN) ? bsum[l] : 0;
    int x = v;
    #pragma unroll
    for (int off = 1; off < 64; off <<= 1) {
        int y = __shfl_up(x, off);
        if (l >= off) x += y;
    }
    if (l < NB_SCAN) bo[l] = x - v;
    if (l == 63) rowptr[N_NODES] = x;
}

__global__ __launch_bounds__(1024) void scan_apply_kernel(const int* __restrict__ cnt,
        const int* __restrict__ bo, int* __restrict__ rowptr,
        float* __restrict__ dis) {
    __shared__ int wsum[16];
    int tid = threadIdx.x, i = blockIdx.x * 1024 + tid;
    int lane = tid & 63, wid = tid >> 6;
    int v = (i < N_NODES) ? cnt[i] : 0;
    int x = v;
    #pragma unroll
    for (int off = 1; off < 64; off <<= 1) {
        int y = __shfl_up(x, off);
        if (lane >= off) x += y;
    }
    if (lane == 63) wsum[wid] = x;
    __syncthreads();
    if (tid == 0) {
        int s = 0;
        #pragma unroll
        for (int w = 0; w < 16; ++w) { int t = wsum[w]; wsum[w] = s; s += t; }
    }
    __syncthreads();
    int excl = bo[blockIdx.x] + wsum[wid] + (x - v);
    if (i < N_NODES) {
        rowptr[i] = excl;
        dis[i] = rsqrtf((float)(v + 1));
    }
}

// Pass 2: atomic-free placement. Stores have no dependent consumers -> full MLP.

__global__ void fill_kernel(const int* __restrict__ ei, const int* __restrict__ loc,
                            const int* __restrict__ rowptr, int* __restrict__ col) {
    int stride = gridDim.x * blockDim.x;
    for (int e = blockIdx.x * blockDim.x + threadIdx.x; e < N_EDGES; e += stride) {
        int s = ei[e];
        int d = ei[N_EDGES + e];
        col[rowptr[d] + loc[e]] = s;
    }
}

// ---------------- weight prep ----------------
// W1b  = bf16(W1)  row-major [128][256]  (B-operand layout for gemm1)
// Wctb = bf16 concat rows: [0..63]=Wmu[64][128], [64..127]=Wlv  (B-operand for gemm2)

__global__ void wprep_kernel(const float* __restrict__ W1, const float* __restrict__ Wmu,
                             const float* __restrict__ Wlv, short* __restrict__ W1b,
                             short* __restrict__ Wctb) {
    int tid = blockIdx.x * blockDim.x + threadIdx.x;
    if (tid < DHID * DIN) {
        W1b[tid] = f2bf(W1[tid]);
    } else if (tid < DHID * DIN + 2 * DOUT * DHID) {
        int t = tid - DHID * DIN;
        Wctb[t] = f2bf((t < DOUT * DHID) ? Wmu[t] : Wlv[t - DOUT * DHID]);
    }
}

// ---------------- GEMM1 (MFMA bf16): u1b[n] = bf16(dis[n] * (x[n] @ W1^T)) ----------------

__global__ __launch_bounds__(256) void gemm1_mfma_kernel(const float* __restrict__ x,
        const short* __restrict__ W1b, const float* __restrict__ dis,
        short* __restrict__ u1b) {
    const int lane = threadIdx.x & 63, w = threadIdx.x >> 6;
    const int l15 = lane & 15, kg = lane >> 4;
    const int nb = blockIdx.x * 64;
    const int r0 = nb + w * 16 + l15;
    const bool valid = r0 < N_NODES;
    const float* xrow = x + (size_t)r0 * DIN;

    f32x4 acc[8] = {};
    #pragma unroll
    for (int ks = 0; ks < 8; ++ks) {
        const int k0 = ks * 32 + kg * 8;
        short8 a;
        if (valid) {
            float4 f0 = *(const float4*)(xrow + k0);
            float4 f1 = *(const float4*)(xrow + k0 + 4);
            a[0] = f2bf(f0.x); a[1] = f2bf(f0.y); a[2] = f2bf(f0.z); a[3] = f2bf(f0.w);
            a[4] = f2bf(f1.x); a[5] = f2bf(f1.y); a[6] = f2bf(f1.z); a[7] = f2bf(f1.w);
        } else {
            a = short8{0, 0, 0, 0, 0, 0, 0, 0};
        }
        #pragma unroll
        for (int c = 0; c < 8; ++c) {
            short8 b = *(const short8*)(W1b + (size_t)(c * 16 + l15) * DIN + k0);
            acc[c] = __builtin_amdgcn_mfma_f32_16x16x32_bf16(a, b, acc[c], 0, 0, 0);
        }
    }

    const int rb = nb + w * 16 + kg * 4;
    float dv[4];
    #pragma unroll
    for (int e = 0; e < 4; ++e) dv[e] = (rb + e < N_NODES) ? dis[rb + e] : 0.f;
    #pragma unroll
    for (int c = 0; c < 8; ++c) {
        #pragma unroll
        for (int e = 0; e < 4; ++e) {
            int r = rb + e;
            if (r < N_NODES)
                u1b[(size_t)r * DHID + c * 16 + l15] = f2bf(acc[c][e] * dv[e]);
        }
    }
}

// ---------------- pull aggregation (one wave per node, bf16 in, bf16 out) ----------------
// col hoisted to registers (1 vector load / 64 edges, shfl-broadcast);
// gather unrolled x8 => 8 independent 256B row-loads in flight per wave.

template <bool LAYER1>
__global__ __launch_bounds__(256) void pull_kernel(const int* __restrict__ rowptr,
        const int* __restrict__ col, const short* __restrict__ uin,
        const float* __restrict__ dis, const float* __restrict__ b1,
        unsigned* __restrict__ uout) {
    const int wid = threadIdx.x >> 6, lane = threadIdx.x & 63;
    const int i = blockIdx.x * 4 + wid;
    if (i >= N_NODES) return;
    const int beg = rowptr[i], end = rowptr[i + 1];
    const unsigned* __restrict__ up = (const unsigned*)uin;   // row stride 64 dwords
    float ax = 0.f, ay = 0.f;
    for (int base = beg; base < end; base += 64) {
        const int rem = end - base;
        const int m = rem < 64 ? rem : 64;
        int cv = (lane < m) ? col[base + lane] : 0;
        int t = 0;
        for (; t + 8 <= m; t += 8) {
            int c0 = __shfl(cv, t);
            int c1 = __shfl(cv, t + 1);
            int c2 = __shfl(cv, t + 2);
            int c3 = __shfl(cv, t + 3);
            int c4 = __shfl(cv, t + 4);
            int c5 = __shfl(cv, t + 5);
            int c6 = __shfl(cv, t + 6);
            int c7 = __shfl(cv, t + 7);
            unsigned v0 = up[(size_t)c0 * 64 + lane];
            unsigned v1 = up[(size_t)c1 * 64 + lane];
            unsigned v2 = up[(size_t)c2 * 64 + lane];
            unsigned v3 = up[(size_t)c3 * 64 + lane];
            unsigned v4 = up[(size_t)c4 * 64 + lane];
            unsigned v5 = up[(size_t)c5 * 64 + lane];
            unsigned v6 = up[(size_t)c6 * 64 + lane];
            unsigned v7 = up[(size_t)c7 * 64 + lane];
            ax += bflo(v0); ay += bfhi(v0);
            ax += bflo(v1); ay += bfhi(v1);
            ax += bflo(v2); ay += bfhi(v2);
            ax += bflo(v3); ay += bfhi(v3);
            ax += bflo(v4); ay += bfhi(v4);
            ax += bflo(v5); ay += bfhi(v5);
            ax += bflo(v6); ay += bfhi(v6);
            ax += bflo(v7); ay += bfhi(v7);
        }
        for (; t + 4 <= m; t += 4) {
            int c0 = __shfl(cv, t);
            int c1 = __shfl(cv, t + 1);
            int c2 = __shfl(cv, t + 2);
            int c3 = __shfl(cv, t + 3);
            unsigned v0 = up[(size_t)c0 * 64 + lane];
            unsigned v1 = up[(size_t)c1 * 64 + lane];
            unsigned v2 = up[(size_t)c2 * 64 + lane];
            unsigned v3 = up[(size_t)c3 * 64 + lane];
            ax += bflo(v0); ay += bfhi(v0);
            ax += bflo(v1); ay += bfhi(v1);
            ax += bflo(v2); ay += bfhi(v2);
            ax += bflo(v3); ay += bfhi(v3);
        }
        for (; t < m; ++t) {
            int c = __shfl(cv, t);
            unsigned v = up[(size_t)c * 64 + lane];
            ax += bflo(v); ay += bfhi(v);
        }
    }
    const float di = dis[i];
    const unsigned sv = up[(size_t)i * 64 + lane];
    float tx = di * (ax + bflo(sv));
    float ty = di * (ay + bfhi(sv));
    if (LAYER1) {
        float2 b = *(const float2*)(b1 + lane * 2);
        tx = fmaxf(tx + b.x, 0.f) * di;
        ty = fmaxf(ty + b.y, 0.f) * di;
    }
    unsigned o = ((unsigned)(unsigned short)f2bf(tx)) |
                 (((unsigned)(unsigned short)f2bf(ty)) << 16);
    uout[(size_t)i * 64 + lane] = o;
}

// ---------------- GEMM2 (MFMA bf16): [mu|lv] = a2b @ Wctb^T + [bmu|blv] ----------------

__global__ __launch_bounds__(256) void gemm2_mfma_kernel(const short* __restrict__ a2b,
        const short* __restrict__ Wctb, const float* __restrict__ bmu,
        const float* __restrict__ blv, float* __restrict__ out) {
    const int lane = threadIdx.x & 63, w = threadIdx.x >> 6;
    const int l15 = lane & 15, kg = lane >> 4;
    const int nb = blockIdx.x * 64;
    const int r0 = nb + w * 16 + l15;
    const bool valid = r0 < N_NODES;
    const short* arow = a2b + (size_t)r0 * DHID;

    f32x4 acc[8] = {};
    #pragma unroll
    for (int ks = 0; ks < 4; ++ks) {
        const int k0 = ks * 32 + kg * 8;
        short8 a = valid ? *(const short8*)(arow + k0)
                         : short8{0, 0, 0, 0, 0, 0, 0, 0};
        #pragma unroll
        for (int c = 0; c < 8; ++c) {
            short8 b = *(const short8*)(Wctb + (size_t)(c * 16 + l15) * DHID + k0);
            acc[c] = __builtin_amdgcn_mfma_f32_16x16x32_bf16(a, b, acc[c], 0, 0, 0);
        }
    }

    float bias[8];
    #pragma unroll
    for (int c = 0; c < 8; ++c) {
        int j = c * 16 + l15;
        bias[c] = (j < DOUT) ? bmu[j] : blv[j - DOUT];
    }
    const int rb = nb + w * 16 + kg * 4;
    #pragma unroll
    for (int c = 0; c < 8; ++c) {
        const int j = c * 16 + l15;
        float* dst = (j < DOUT) ? (out + j)
                                : (out + (size_t)N_NODES * DOUT + (j - DOUT));
        #pragma unroll
        for (int e = 0; e < 4; ++e) {
            int r = rb + e;
            if (r < N_NODES)
                dst[(size_t)r * DOUT] = acc[c][e] + bias[c];
        }
    }
}

// ---------------- launcher ----------------

extern "C" void kernel_launch(void* const* d_in, const int* in_sizes, int n_in,
                              void* d_out, int out_size, void* d_ws, size_t ws_size,
                              hipStream_t stream) {
    const float* x   = (const float*)d_in[0];
    const int*   ei  = (const int*)d_in[1];
    const float* W1  = (const float*)d_in[2];
    const float* b1  = (const float*)d_in[3];
    const float* Wmu = (const float*)d_in[4];
    const float* bmu = (const float*)d_in[5];
    const float* Wlv = (const float*)d_in[6];
    const float* blv = (const float*)d_in[7];
    float* out = (float*)d_out;

    char* ws = (char*)d_ws;
    size_t off = 0;
    auto alloc = [&](size_t bytes) -> char* {
        char* p = ws + off;
        off += (bytes + 255) & ~(size_t)255;
        return p;
    };
    int*   cnt    = (int*)  alloc((size_t)N_NODES * 4);
    int*   rowptr = (int*)  alloc((size_t)(N_NODES + 1) * 4);
    float* dis    = (float*)alloc((size_t)N_NODES * 4);
    int*   loc    = (int*)  alloc((size_t)N_EDGES * 4);
    int*   col    = (int*)  alloc((size_t)N_EDGES * 4);
    int*   bsum   = (int*)  alloc((size_t)NB_SCAN * 4);
    int*   bo     = (int*)  alloc((size_t)NB_SCAN * 4);
    short* W1b    = (short*)alloc((size_t)DHID * DIN * 2);
    short* Wctb   = (short*)alloc((size_t)2 * DOUT * DHID * 2);
    short* u1b    = (short*)alloc((size_t)N_NODES * DHID * 2);
    short* u2b    = (short*)alloc((size_t)N_NODES * DHID * 2);
    short* a2b    = (short*)alloc((size_t)N_NODES * DHID * 2);

    hipMemsetAsync(cnt, 0, (size_t)N_NODES * 4, stream);
    wprep_kernel<<<192, 256, 0, stream>>>(W1, Wmu, Wlv, W1b, Wctb);
    count_kernel<<<1024, 256, 0, stream>>>(ei, cnt, loc);
    bsum_kernel<<<NB_SCAN, 1024, 0, stream>>>(cnt, bsum);
    bscan_kernel<<<1, 64, 0, stream>>>(bsum, bo, rowptr);
    scan_apply_kernel<<<NB_SCAN, 1024, 0, stream>>>(cnt, bo, rowptr, dis);
    fill_kernel<<<1024, 256, 0, stream>>>(ei, loc, rowptr, col);
    gemm1_mfma_kernel<<<(N_NODES + 63) / 64, 256, 0, stream>>>(x, W1b, dis, u1b);
    pull_kernel<true><<<N_NODES / 4, 256, 0, stream>>>(rowptr, col, u1b, dis, b1,
                                                       (unsigned*)u2b);
    pull_kernel<false><<<N_NODES / 4, 256, 0, stream>>>(rowptr, col, u2b, dis, nullptr,
                                                        (unsigned*)a2b);
    gemm2_mfma_kernel<<<(N_NODES + 63) / 64, 256, 0, stream>>>(a2b, Wctb, bmu, blv, out);
}